// Round 16
// baseline (193.880 us; speedup 1.0000x reference)
//
#include <hip/hip_runtime.h>
#include <hip/hip_fp16.h>
#include <math.h>

#define T_LEN 8192
#define CHN 128
#define BATCH 16
#define NKCHUNK 16   // k-chunk = 512 -> grid 16x16 = 256 blocks (1/CU)
#define KSTAGE 32    // k elems per LDS stage
#define NITER (T_LEN / NKCHUNK / KSTAGE)   // = 16 stage iterations per block

typedef short bf16x8 __attribute__((ext_vector_type(8)));
typedef float f32x16 __attribute__((ext_vector_type(16)));

// Native-vector complex type -> packed v_pk_* fp32 codegen (R8: -3 us fft).
typedef float cplx __attribute__((ext_vector_type(2)));
__device__ __forceinline__ cplx C2(float x, float y) { cplx r; r.x = x; r.y = y; return r; }

#define SIN8 0.3826834323650898f
#define COS8 0.9238795325112868f

// zc/zs K-CHUNKED layout [b][t>>6][chan][t&63] (R17: contiguous gram reads).
#define TCHUNK 8192              // ushorts per [tc] slab: 128 chan x 64 k
#define BPLANE (128 * TCHUNK)    // ushorts per batch per plane (= CHN*T_LEN)

// gram LDS geometry: KSTAGE=32 -> plane = 128 rows x 32 k = 8 KiB.
#define GSP 4096                 // ushorts per plane (8 KiB)
#define GBUF (2 * GSP)           // ushorts per buffer (zc+zs planes, 16 KiB)
#define NBUF 8                   // depth-8 pipeline, 8 x 16 KiB = 128 KiB LDS

typedef const __attribute__((address_space(1))) uint gld_src_t;
typedef __attribute__((address_space(3))) uint gld_dst_t;

__device__ __forceinline__ ushort f2bf(float f) {
    unsigned u = __float_as_uint(f);
    unsigned r = (u + 0x7fffu + ((u >> 16) & 1u)) >> 16;
    return (ushort)r;
}

__device__ __forceinline__ void barrier_lds_only() {
    asm volatile("s_waitcnt lgkmcnt(0)" ::: "memory");
    __builtin_amdgcn_s_barrier();
}

__device__ __forceinline__ cplx cmul(cplx a, cplx b) {
    cplx t = a.yy * b.yx;            // {ay*by, ay*bx}  (pk_mul)
    cplx r = a.xx * b;               // {ax*bx, ax*by}  (pk_mul)
    return C2(r.x - t.x, r.y + t.y);
}

__device__ __forceinline__ void r4f(cplx x0, cplx x1, cplx x2, cplx x3,
                                    cplx wa, cplx wb, cplx wc,
                                    cplx& y0, cplx& y1, cplx& y2, cplx& y3) {
    cplx t0 = x0 + x2, t1 = x0 - x2;
    cplx t2 = x1 + x3, t3 = x1 - x3;
    y0 = t0 + t2;
    y1 = cmul(t0 - t2, wb);
    y2 = cmul(C2(t1.x + t3.y, t1.y - t3.x), wa);
    y3 = cmul(C2(t1.x - t3.y, t1.y + t3.x), wc);
}

__device__ __forceinline__ void r4i(cplx x0, cplx x1, cplx x2, cplx x3,
                                    cplx wa, cplx wb, cplx wc,
                                    cplx& y0, cplx& y1, cplx& y2, cplx& y3) {
    cplx a1 = cmul(x1, wb);
    cplx a2 = cmul(x2, wa);
    cplx a3 = cmul(x3, wc);
    cplx u0 = x0 + a1, u1 = x0 - a1;
    cplx p = a2 + a3;
    cplx m = C2(-(a2.y - a3.y), a2.x - a3.x);
    y0 = u0 + p; y2 = u0 - p;
    y1 = u1 + m; y3 = u1 - m;
}

__device__ __forceinline__ void r8f(const cplx* x, float sn, float cs, cplx* y) {
    const float r22 = 0.70710678118654752f;
    cplx w1 = C2(cs, sn);
    cplx w2 = C2(cs * cs - sn * sn, 2.f * cs * sn);
    cplx w4 = cmul(w2, w2);
    cplx w6 = cmul(w4, w2);
    cplx u0 = x[0] + x[4], u1 = x[1] + x[5], u2 = x[2] + x[6], u3 = x[3] + x[7];
    cplx e0 = cmul(x[0] - x[4], w1);
    cplx e1 = cmul(x[1] - x[5], w1);
    cplx e2 = cmul(x[2] - x[6], w1);
    cplx e3 = cmul(x[3] - x[7], w1);
    cplx v0 = e0;
    cplx v1 = C2(r22 * (e1.x + e1.y), r22 * (e1.y - e1.x));
    cplx v2 = C2(e2.y, -e2.x);
    cplx v3 = C2(r22 * (e3.y - e3.x), -r22 * (e3.x + e3.y));
    r4f(u0, u1, u2, u3, w2, w4, w6, y[0], y[1], y[2], y[3]);
    r4f(v0, v1, v2, v3, w2, w4, w6, y[4], y[5], y[6], y[7]);
}

// Pass-A specialization: inputs pure real (imag = 0).
__device__ __forceinline__ void r8f_real(const float* x, float sn, float cs, cplx* y) {
    const float r22 = 0.70710678118654752f;
    cplx w2 = C2(cs * cs - sn * sn, 2.f * cs * sn);
    cplx w4 = cmul(w2, w2);
    cplx w6 = cmul(w4, w2);
    float u0 = x[0] + x[4], u1 = x[1] + x[5], u2 = x[2] + x[6], u3 = x[3] + x[7];
    float d0 = x[0] - x[4], d1 = x[1] - x[5], d2 = x[2] - x[6], d3 = x[3] - x[7];
    cplx e1 = C2(d1 * cs, d1 * sn);
    cplx e2 = C2(d2 * cs, d2 * sn);
    cplx e3 = C2(d3 * cs, d3 * sn);
    cplx v0 = C2(d0 * cs, d0 * sn);
    cplx v1 = C2(r22 * (e1.x + e1.y), r22 * (e1.y - e1.x));
    cplx v2 = C2(e2.y, -e2.x);
    cplx v3 = C2(r22 * (e3.y - e3.x), -r22 * (e3.x + e3.y));
    float t0 = u0 + u2, t1 = u0 - u2, t2 = u1 + u3, t3 = u1 - u3;
    y[0] = C2(t0 + t2, 0.f);
    float s1 = t0 - t2;
    y[1] = C2(s1 * w4.x, s1 * w4.y);
    y[2] = cmul(C2(t1, -t3), w2);
    y[3] = cmul(C2(t1, t3), w6);
    r4f(v0, v1, v2, v3, w2, w4, w6, y[4], y[5], y[6], y[7]);
}

__device__ __forceinline__ void r8i(const cplx* x, float sn, float cs, cplx* y) {
    const float r22 = 0.70710678118654752f;
    cplx w1 = C2(cs, sn);
    cplx w2 = C2(cs * cs - sn * sn, 2.f * cs * sn);
    cplx w4 = cmul(w2, w2);
    cplx w6 = cmul(w4, w2);
    cplx g0, g1, g2, g3, g4, g5, g6, g7;
    r4i(x[0], x[1], x[2], x[3], w2, w4, w6, g0, g1, g2, g3);
    r4i(x[4], x[5], x[6], x[7], w2, w4, w6, g4, g5, g6, g7);
    cplx t0 = cmul(g4, w1);
    cplx e1 = cmul(g5, w1);
    cplx e2 = cmul(g6, w1);
    cplx e3 = cmul(g7, w1);
    cplx t1 = C2(r22 * (e1.x - e1.y), r22 * (e1.x + e1.y));
    cplx t2 = C2(-e2.y, e2.x);
    cplx t3 = C2(-r22 * (e3.x + e3.y), r22 * (e3.x - e3.y));
    y[0] = g0 + t0; y[4] = g0 - t0;
    y[1] = g1 + t1; y[5] = g1 - t1;
    y[2] = g2 + t2; y[6] = g2 - t2;
    y[3] = g3 + t3; y[7] = g3 - t3;
}

// fft: proven R13/R15 structure (74-75 us across 5 sessions). UNCHANGED.
__global__ __launch_bounds__(512, 4) void fft_analytic_kernel(const float* __restrict__ x,
                                                              ushort* __restrict__ zc,
                                                              ushort* __restrict__ zs) {
    __shared__ __align__(16) cplx buf[T_LEN];   // 64 KiB
    const int tid = threadIdx.x;
    const int row = blockIdx.x;
    const float* xr = x + ((size_t)row << 13);

    // fwd pass Q=1024 fused with global load (x real; imag folds away)
    for (int s = 0; s < 2; ++s) {
        const int g = tid + (s << 9);
        float X[8];
        cplx Y[8];
#pragma unroll
        for (int c = 0; c < 8; ++c) X[c] = xr[g + (c << 10)];
        float sn, cs;
        __sincosf(-(float)M_PI / 4096.f * (float)g, &sn, &cs);
        r8f_real(X, sn, cs, Y);
#pragma unroll
        for (int c = 0; c < 8; ++c) buf[g + (c << 10)] = Y[c];
    }
    __syncthreads();

    // fwd LDS pass Q=128 (sincos hoisted; j s-invariant)
    {
        const int j = tid & 127;
        float sn, cs;
        __sincosf(-(float)M_PI / 512.f * (float)j, &sn, &cs);
        for (int s = 0; s < 2; ++s) {
            const int g = tid + (s << 9);
            const int i = ((g & ~127) << 3) | j;
            cplx xx[8], yy[8];
#pragma unroll
            for (int c = 0; c < 8; ++c) xx[c] = buf[i + c * 128];
            r8f(xx, sn, cs, yy);
#pragma unroll
            for (int c = 0; c < 8; ++c) buf[i + c * 128] = yy[c];
        }
        __syncthreads();
    }

    // fwd LDS pass Q=16: plain reads, swizzled writes (slot = idx ^ 2c)
    {
        const int j = tid & 15;
        float sn, cs;
        __sincosf(-(float)M_PI / 64.f * (float)j, &sn, &cs);
        for (int s = 0; s < 2; ++s) {
            const int g = tid + (s << 9);
            const int i = ((g & ~15) << 3) | j;
            cplx xx[8], yy[8];
#pragma unroll
            for (int c = 0; c < 8; ++c) xx[c] = buf[i + c * 16];
            r8f(xx, sn, cs, yy);
#pragma unroll
            for (int c = 0; c < 8; ++c) buf[(i + c * 16) ^ (2 * c)] = yy[c];
        }
        __syncthreads();
    }

    // register-local middle: thread owns elements [16*tid, 16*tid+16).
    {
        cplx v[16];
        float4* bb = (float4*)buf;
        const int K = tid & 7;
#pragma unroll
        for (int p = 0; p < 8; ++p) {
            float4 f = bb[8 * tid + (p ^ K)];
            v[2 * p]     = C2(f.x, f.y);
            v[2 * p + 1] = C2(f.z, f.w);
        }
        cplx xe[8], xo[8], E[8], O[8], t[8];
#pragma unroll
        for (int c = 0; c < 8; ++c) { xe[c] = v[2 * c]; xo[c] = v[2 * c + 1]; }
        r8f(xe, 0.f, 1.f, E);
        r8f(xo, -SIN8, COS8, O);
#pragma unroll
        for (int c = 0; c < 8; ++c) t[c] = E[c] + O[c];   // dist-1 + mask fuse
        r8i(t, 0.f, 1.f, xe);
        r8i(t, SIN8, COS8, xo);
#pragma unroll
        for (int p = 0; p < 8; ++p)
            bb[8 * tid + (p ^ K)] = make_float4(xe[p].x, xe[p].y, xo[p].x, xo[p].y);
    }
    __syncthreads();

    // inv LDS pass Q=16: swizzled reads, plain writes
    {
        const int j = tid & 15;
        float sn, cs;
        __sincosf((float)M_PI / 64.f * (float)j, &sn, &cs);
        for (int s = 0; s < 2; ++s) {
            const int g = tid + (s << 9);
            const int i = ((g & ~15) << 3) | j;
            cplx xx[8], yy[8];
#pragma unroll
            for (int c = 0; c < 8; ++c) xx[c] = buf[(i + c * 16) ^ (2 * c)];
            r8i(xx, sn, cs, yy);
#pragma unroll
            for (int c = 0; c < 8; ++c) buf[i + c * 16] = yy[c];
        }
        __syncthreads();
    }

    // inv LDS pass Q=128
    {
        const int j = tid & 127;
        float sn, cs;
        __sincosf((float)M_PI / 512.f * (float)j, &sn, &cs);
        for (int s = 0; s < 2; ++s) {
            const int g = tid + (s << 9);
            const int i = ((g & ~127) << 3) | j;
            cplx xx[8], yy[8];
#pragma unroll
            for (int c = 0; c < 8; ++c) xx[c] = buf[i + c * 128];
            r8i(xx, sn, cs, yy);
#pragma unroll
            for (int c = 0; c < 8; ++c) buf[i + c * 128] = yy[c];
        }
        __syncthreads();
    }

    // final inv pass Q=1024 fused with normalize + K-CHUNKED store
    {
        const size_t base = ((size_t)(row >> 7) * BPLANE) + (size_t)(row & 127) * 64;
        ushort* zcr = zc + base;
        ushort* zsr = zs + base;
        const int tk = tid & 63;
        const int tcb = tid >> 6;
        for (int s = 0; s < 2; ++s) {
            const int g = tid + (s << 9);
            cplx xx[8], yy[8];
#pragma unroll
            for (int c = 0; c < 8; ++c) xx[c] = buf[g + (c << 10)];
            float sn, cs;
            __sincosf((float)M_PI / 4096.f * (float)g, &sn, &cs);
            r8i(xx, sn, cs, yy);
#pragma unroll
            for (int c = 0; c < 8; ++c) {
                cplx vv = yy[c];
                float n2 = vv.x * vv.x + vv.y * vv.y;
                float cc = 1.f, ss = 0.f;
                if (n2 > 0.f) { float inv = rsqrtf(n2); cc = vv.x * inv; ss = vv.y * inv; }
                const int tc = tcb + s * 8 + c * 16;          // t>>6
                zcr[(size_t)tc * TCHUNK + tk] = f2bf(cc);
                zsr[(size_t)tc * TCHUNK + tk] = f2bf(ss);
            }
        }
    }
}

// MFMA Gram partials — R23 DIAGNOSTIC: run the ENTIRE pipeline TWICE
// (identical math, acc accumulates both passes, 0.5x scale at C-write).
// Purpose: gram has been counter-invisible since R7 because the top-5
// table ranks ALL dispatches and every bench iteration contributes an
// fft at 73-95 us — gram at ~65 us can never surface. Doubling its
// duration (~130 us) forces it into the top-5 WITH its counter set.
// Numerically safe: acc <= ~1024 << half-max; extra rounding ~2^-20.
// PRE-COMMITTED interpretation: MfmaUtil>40% -> MFMA-bound (symmetry
// halving next); VALUBusy high -> VALU overhead; both low + FETCH~134GB
// slow -> memory-concurrency; LDS_BANK_CONFLICT large -> swizzle wrong;
// all low @25% occ -> latency -> raise occupancy.
__global__ __launch_bounds__(512, 2) void gram_kernel(const ushort* __restrict__ zc,
                                                      const ushort* __restrict__ zs,
                                                      __half2* __restrict__ partial) {
    const int b = blockIdx.x, kc = blockIdx.y;
    const int tid = threadIdx.x;
    const int wave = tid >> 6;
    const int lane = tid & 63;
    const int wr = wave & 3, wcol = wave >> 2;
    const int lane31 = tid & 31;
    const int half = (tid >> 5) & 1;

    __shared__ __align__(16) ushort sZ[NBUF * GBUF];   // 128 KiB

    f32x16 accRe[2], accIm[2];
#pragma unroll
    for (int v = 0; v < 2; ++v)
#pragma unroll
        for (int r = 0; r < 16; ++r) { accRe[v][r] = 0.f; accIm[v][r] = 0.f; }

    const size_t base = (size_t)b * BPLANE + (size_t)kc * 8 * TCHUNK;

    const ushort* gsrc[2];
    int lbase[2];
#pragma unroll
    for (int q = 0; q < 2; ++q) {
        int L = (q * 8 + wave) * 64 + lane;   // 0..1023
        int plane = L >> 9;
        int P = L & 511;
        int g = P >> 6;
        int s = P & 63;
        int r = g * 16 + (s & 15);
        int c = (s >> 4) ^ (r & 3);
        gsrc[q] = (plane ? zs : zc) + base + (size_t)r * 64 + (size_t)c * 8;
        lbase[q] = (q * 8 + wave) * 512;
    }

#define STAGE(IT, BUF) do {                                                        \
        _Pragma("unroll")                                                          \
        for (int q = 0; q < 2; ++q)                                                \
            __builtin_amdgcn_global_load_lds(                                      \
                (gld_src_t*)(gsrc[q] + (size_t)((IT) >> 1) * TCHUNK                \
                                     + (size_t)((IT) & 1) * 32),                   \
                (gld_dst_t*)&sZ[(BUF) * GBUF + lbase[q]], 16, 0, 0);               \
    } while (0)

    for (int rep = 0; rep < 2; ++rep) {
        STAGE(0, 0); STAGE(1, 1); STAGE(2, 2); STAGE(3, 3);
        STAGE(4, 4); STAGE(5, 5); STAGE(6, 6); STAGE(7, 7);

#pragma unroll
        for (int it = 0; it < NITER; ++it) {
            if (it <= NITER - 8)      { asm volatile("s_waitcnt vmcnt(14)" ::: "memory"); }
            else if (it == NITER - 7) { asm volatile("s_waitcnt vmcnt(12)" ::: "memory"); }
            else if (it == NITER - 6) { asm volatile("s_waitcnt vmcnt(10)" ::: "memory"); }
            else if (it == NITER - 5) { asm volatile("s_waitcnt vmcnt(8)"  ::: "memory"); }
            else if (it == NITER - 4) { asm volatile("s_waitcnt vmcnt(6)"  ::: "memory"); }
            else if (it == NITER - 3) { asm volatile("s_waitcnt vmcnt(4)"  ::: "memory"); }
            else if (it == NITER - 2) { asm volatile("s_waitcnt vmcnt(2)"  ::: "memory"); }
            else                      { asm volatile("s_waitcnt vmcnt(0)"  ::: "memory"); }
            __builtin_amdgcn_sched_barrier(0);
            __builtin_amdgcn_s_barrier();

            const ushort* S = sZ + (it & (NBUF - 1)) * GBUF;
#pragma unroll
            for (int kb = 0; kb < KSTAGE; kb += 16) {
                const int cA = (kb >> 3) + half;                   // chunk 0..3
                const int rowA = wr * 32 + lane31;
                const int aoff = ((rowA >> 4) << 9) + ((cA ^ (rowA & 3)) << 7) + ((rowA & 15) << 3);
                bf16x8 aC = *(const bf16x8*)&S[aoff];
                bf16x8 aS = *(const bf16x8*)&S[GSP + aoff];
                bf16x8 aCn;
#pragma unroll
                for (int r = 0; r < 8; ++r) aCn[r] = (short)(aC[r] ^ (short)0x8000);
                bf16x8 bC[2], bS[2];
#pragma unroll
                for (int v = 0; v < 2; ++v) {
                    const int rowB = wcol * 64 + v * 32 + lane31;
                    const int boff = ((rowB >> 4) << 9) + ((cA ^ (rowB & 3)) << 7) + ((rowB & 15) << 3);
                    bC[v] = *(const bf16x8*)&S[boff];
                    bS[v] = *(const bf16x8*)&S[GSP + boff];
                }
                accRe[0] = __builtin_amdgcn_mfma_f32_32x32x16_bf16(aC,  bC[0], accRe[0], 0, 0, 0);
                accRe[1] = __builtin_amdgcn_mfma_f32_32x32x16_bf16(aC,  bC[1], accRe[1], 0, 0, 0);
                accIm[0] = __builtin_amdgcn_mfma_f32_32x32x16_bf16(aS,  bC[0], accIm[0], 0, 0, 0);
                accIm[1] = __builtin_amdgcn_mfma_f32_32x32x16_bf16(aS,  bC[1], accIm[1], 0, 0, 0);
                accRe[0] = __builtin_amdgcn_mfma_f32_32x32x16_bf16(aS,  bS[0], accRe[0], 0, 0, 0);
                accRe[1] = __builtin_amdgcn_mfma_f32_32x32x16_bf16(aS,  bS[1], accRe[1], 0, 0, 0);
                accIm[0] = __builtin_amdgcn_mfma_f32_32x32x16_bf16(aCn, bS[0], accIm[0], 0, 0, 0);
                accIm[1] = __builtin_amdgcn_mfma_f32_32x32x16_bf16(aCn, bS[1], accIm[1], 0, 0, 0);
            }

            barrier_lds_only();
            if (it + NBUF < NITER) STAGE(it + NBUF, it & (NBUF - 1));
        }
    }
#undef STAGE

    // C/D layout (verified m74/m101): col=lane&31, row=(reg&3)+8*(reg>>2)+4*(lane>>5)
    // 0.5x scale compensates the rep x2 accumulation.
    __half2* pb = partial + ((size_t)(kc * BATCH + b) << 14);
#pragma unroll
    for (int v = 0; v < 2; ++v)
#pragma unroll
        for (int r = 0; r < 16; ++r) {
            int rrow = (r & 3) + 8 * (r >> 2) + 4 * half;
            int i = wr * 32 + rrow;
            int j = wcol * 64 + v * 32 + lane31;
            pb[i * CHN + j] = __floats2half2_rn(0.5f * accRe[v][r], 0.5f * accIm[v][r]);
        }
}

// Vectorized reduce — 4 outputs/thread, uint4 loads, float4 store.
__global__ __launch_bounds__(256) void reduce_kernel(const __half2* __restrict__ partial,
                                                     float* __restrict__ out) {
    const size_t n = (size_t)BATCH * CHN * CHN;
    const size_t i4 = ((size_t)blockIdx.x * 256 + threadIdx.x) * 4;
    if (i4 >= n) return;
    float re[4] = {0.f, 0.f, 0.f, 0.f}, im[4] = {0.f, 0.f, 0.f, 0.f};
#pragma unroll
    for (int c = 0; c < NKCHUNK; ++c) {
        uint4 u = *(const uint4*)&partial[(size_t)c * n + i4];
        const __half2* h = (const __half2*)&u;
#pragma unroll
        for (int k = 0; k < 4; ++k) {
            float2 p = __half22float2(h[k]);
            re[k] += p.x;
            im[k] += p.y;
        }
    }
    float4 o;
    o.x = sqrtf(re[0] * re[0] + im[0] * im[0]) * (1.0f / (float)T_LEN);
    o.y = sqrtf(re[1] * re[1] + im[1] * im[1]) * (1.0f / (float)T_LEN);
    o.z = sqrtf(re[2] * re[2] + im[2] * im[2]) * (1.0f / (float)T_LEN);
    o.w = sqrtf(re[3] * re[3] + im[3] * im[3]) * (1.0f / (float)T_LEN);
    *(float4*)&out[i4] = o;
}

extern "C" void kernel_launch(void* const* d_in, const int* in_sizes, int n_in,
                              void* d_out, int out_size, void* d_ws, size_t ws_size,
                              hipStream_t stream) {
    const float* x = (const float*)d_in[0];
    float* out = (float*)d_out;

    const size_t plane_elems = (size_t)BATCH * CHN * T_LEN;                 // 16.8M
    ushort* zc = (ushort*)d_ws;                                             // 33.55 MB
    ushort* zs = zc + plane_elems;                                          // +33.55 MB
    __half2* partial = (__half2*)((char*)d_ws + 2 * plane_elems * sizeof(ushort)); // +16.78 MB (NKCHUNK=16)

    fft_analytic_kernel<<<BATCH * CHN, 512, 0, stream>>>(x, zc, zs);

    dim3 g2(BATCH, NKCHUNK);
    gram_kernel<<<g2, 512, 0, stream>>>(zc, zs, partial);

    const int n_out = BATCH * CHN * CHN;                                    // 262144
    reduce_kernel<<<n_out / (256 * 4), 256, 0, stream>>>(partial, out);
}

// Round 17
// 180.704 us; speedup vs baseline: 1.0729x; 1.0729x over previous
//
#include <hip/hip_runtime.h>
#include <hip/hip_fp16.h>
#include <math.h>

#define T_LEN 8192
#define CHN 128
#define BATCH 16
#define NKCHUNK 32   // k-chunk = 256 -> grid 16x32 = 512 blocks (2/CU) — best-evidenced era
#define KSTAGE 32    // k elems per LDS stage -> NITER 8, depth-3 pipeline
#define NITER (T_LEN / NKCHUNK / KSTAGE)   // = 8 stage iterations per block

typedef short bf16x8 __attribute__((ext_vector_type(8)));
typedef float f32x16 __attribute__((ext_vector_type(16)));

// Native-vector complex type -> packed v_pk_* fp32 codegen (R8: -3 us fft).
typedef float cplx __attribute__((ext_vector_type(2)));
__device__ __forceinline__ cplx C2(float x, float y) { cplx r; r.x = x; r.y = y; return r; }

#define SIN8 0.3826834323650898f
#define COS8 0.9238795325112868f

// zc/zs K-CHUNKED layout [b][t>>6][chan][t&63] (R17: contiguous gram reads).
#define TCHUNK 8192              // ushorts per [tc] slab: 128 chan x 64 k
#define BPLANE (128 * TCHUNK)    // ushorts per batch per plane (= CHN*T_LEN)

// gram LDS geometry: KSTAGE=32 -> plane = 128 rows x 32 k = 8 KiB.
// Column-major swizzle: chunk (r,c) at group offset (c^(r&3))*256B +
// (r&15)*16B within the (r>>4) 1-KiB group.
#define GSP 4096                 // ushorts per plane (8 KiB)
#define GBUF (2 * GSP)           // ushorts per buffer (zc+zs planes, 16 KiB)

typedef const __attribute__((address_space(1))) uint gld_src_t;
typedef __attribute__((address_space(3))) uint gld_dst_t;

__device__ __forceinline__ ushort f2bf(float f) {
    unsigned u = __float_as_uint(f);
    unsigned r = (u + 0x7fffu + ((u >> 16) & 1u)) >> 16;
    return (ushort)r;
}

__device__ __forceinline__ void barrier_lds_only() {
    asm volatile("s_waitcnt lgkmcnt(0)" ::: "memory");
    __builtin_amdgcn_s_barrier();
}

__device__ __forceinline__ cplx cmul(cplx a, cplx b) {
    cplx t = a.yy * b.yx;            // {ay*by, ay*bx}  (pk_mul)
    cplx r = a.xx * b;               // {ax*bx, ax*by}  (pk_mul)
    return C2(r.x - t.x, r.y + t.y);
}

__device__ __forceinline__ void r4f(cplx x0, cplx x1, cplx x2, cplx x3,
                                    cplx wa, cplx wb, cplx wc,
                                    cplx& y0, cplx& y1, cplx& y2, cplx& y3) {
    cplx t0 = x0 + x2, t1 = x0 - x2;
    cplx t2 = x1 + x3, t3 = x1 - x3;
    y0 = t0 + t2;
    y1 = cmul(t0 - t2, wb);
    y2 = cmul(C2(t1.x + t3.y, t1.y - t3.x), wa);
    y3 = cmul(C2(t1.x - t3.y, t1.y + t3.x), wc);
}

__device__ __forceinline__ void r4i(cplx x0, cplx x1, cplx x2, cplx x3,
                                    cplx wa, cplx wb, cplx wc,
                                    cplx& y0, cplx& y1, cplx& y2, cplx& y3) {
    cplx a1 = cmul(x1, wb);
    cplx a2 = cmul(x2, wa);
    cplx a3 = cmul(x3, wc);
    cplx u0 = x0 + a1, u1 = x0 - a1;
    cplx p = a2 + a3;
    cplx m = C2(-(a2.y - a3.y), a2.x - a3.x);
    y0 = u0 + p; y2 = u0 - p;
    y1 = u1 + m; y3 = u1 - m;
}

__device__ __forceinline__ void r8f(const cplx* x, float sn, float cs, cplx* y) {
    const float r22 = 0.70710678118654752f;
    cplx w1 = C2(cs, sn);
    cplx w2 = C2(cs * cs - sn * sn, 2.f * cs * sn);
    cplx w4 = cmul(w2, w2);
    cplx w6 = cmul(w4, w2);
    cplx u0 = x[0] + x[4], u1 = x[1] + x[5], u2 = x[2] + x[6], u3 = x[3] + x[7];
    cplx e0 = cmul(x[0] - x[4], w1);
    cplx e1 = cmul(x[1] - x[5], w1);
    cplx e2 = cmul(x[2] - x[6], w1);
    cplx e3 = cmul(x[3] - x[7], w1);
    cplx v0 = e0;
    cplx v1 = C2(r22 * (e1.x + e1.y), r22 * (e1.y - e1.x));
    cplx v2 = C2(e2.y, -e2.x);
    cplx v3 = C2(r22 * (e3.y - e3.x), -r22 * (e3.x + e3.y));
    r4f(u0, u1, u2, u3, w2, w4, w6, y[0], y[1], y[2], y[3]);
    r4f(v0, v1, v2, v3, w2, w4, w6, y[4], y[5], y[6], y[7]);
}

// Pass-A specialization: inputs pure real (imag = 0).
__device__ __forceinline__ void r8f_real(const float* x, float sn, float cs, cplx* y) {
    const float r22 = 0.70710678118654752f;
    cplx w2 = C2(cs * cs - sn * sn, 2.f * cs * sn);
    cplx w4 = cmul(w2, w2);
    cplx w6 = cmul(w4, w2);
    float u0 = x[0] + x[4], u1 = x[1] + x[5], u2 = x[2] + x[6], u3 = x[3] + x[7];
    float d0 = x[0] - x[4], d1 = x[1] - x[5], d2 = x[2] - x[6], d3 = x[3] - x[7];
    cplx e1 = C2(d1 * cs, d1 * sn);
    cplx e2 = C2(d2 * cs, d2 * sn);
    cplx e3 = C2(d3 * cs, d3 * sn);
    cplx v0 = C2(d0 * cs, d0 * sn);
    cplx v1 = C2(r22 * (e1.x + e1.y), r22 * (e1.y - e1.x));
    cplx v2 = C2(e2.y, -e2.x);
    cplx v3 = C2(r22 * (e3.y - e3.x), -r22 * (e3.x + e3.y));
    float t0 = u0 + u2, t1 = u0 - u2, t2 = u1 + u3, t3 = u1 - u3;
    y[0] = C2(t0 + t2, 0.f);
    float s1 = t0 - t2;
    y[1] = C2(s1 * w4.x, s1 * w4.y);
    y[2] = cmul(C2(t1, -t3), w2);
    y[3] = cmul(C2(t1, t3), w6);
    r4f(v0, v1, v2, v3, w2, w4, w6, y[4], y[5], y[6], y[7]);
}

__device__ __forceinline__ void r8i(const cplx* x, float sn, float cs, cplx* y) {
    const float r22 = 0.70710678118654752f;
    cplx w1 = C2(cs, sn);
    cplx w2 = C2(cs * cs - sn * sn, 2.f * cs * sn);
    cplx w4 = cmul(w2, w2);
    cplx w6 = cmul(w4, w2);
    cplx g0, g1, g2, g3, g4, g5, g6, g7;
    r4i(x[0], x[1], x[2], x[3], w2, w4, w6, g0, g1, g2, g3);
    r4i(x[4], x[5], x[6], x[7], w2, w4, w6, g4, g5, g6, g7);
    cplx t0 = cmul(g4, w1);
    cplx e1 = cmul(g5, w1);
    cplx e2 = cmul(g6, w1);
    cplx e3 = cmul(g7, w1);
    cplx t1 = C2(r22 * (e1.x - e1.y), r22 * (e1.x + e1.y));
    cplx t2 = C2(-e2.y, e2.x);
    cplx t3 = C2(-r22 * (e3.x + e3.y), r22 * (e3.x - e3.y));
    y[0] = g0 + t0; y[4] = g0 - t0;
    y[1] = g1 + t1; y[5] = g1 - t1;
    y[2] = g2 + t2; y[6] = g2 - t2;
    y[3] = g3 + t3; y[7] = g3 - t3;
}

// fft: proven R13/R15 structure (74-75 us across 5 sessions). UNCHANGED.
// R16 diagnostic established fft as the single largest kernel; its floor is
// structural (VALU-issue ~51 us + stalls), not sincos/bank/ILP-fixable
// (R10, R14, R15 all tested and nulled/regressed).
__global__ __launch_bounds__(512, 4) void fft_analytic_kernel(const float* __restrict__ x,
                                                              ushort* __restrict__ zc,
                                                              ushort* __restrict__ zs) {
    __shared__ __align__(16) cplx buf[T_LEN];   // 64 KiB
    const int tid = threadIdx.x;
    const int row = blockIdx.x;
    const float* xr = x + ((size_t)row << 13);

    // fwd pass Q=1024 fused with global load (x real; imag folds away)
    for (int s = 0; s < 2; ++s) {
        const int g = tid + (s << 9);
        float X[8];
        cplx Y[8];
#pragma unroll
        for (int c = 0; c < 8; ++c) X[c] = xr[g + (c << 10)];
        float sn, cs;
        __sincosf(-(float)M_PI / 4096.f * (float)g, &sn, &cs);
        r8f_real(X, sn, cs, Y);
#pragma unroll
        for (int c = 0; c < 8; ++c) buf[g + (c << 10)] = Y[c];
    }
    __syncthreads();

    // fwd LDS pass Q=128 (sincos hoisted; j s-invariant)
    {
        const int j = tid & 127;
        float sn, cs;
        __sincosf(-(float)M_PI / 512.f * (float)j, &sn, &cs);
        for (int s = 0; s < 2; ++s) {
            const int g = tid + (s << 9);
            const int i = ((g & ~127) << 3) | j;
            cplx xx[8], yy[8];
#pragma unroll
            for (int c = 0; c < 8; ++c) xx[c] = buf[i + c * 128];
            r8f(xx, sn, cs, yy);
#pragma unroll
            for (int c = 0; c < 8; ++c) buf[i + c * 128] = yy[c];
        }
        __syncthreads();
    }

    // fwd LDS pass Q=16: plain reads, swizzled writes (slot = idx ^ 2c)
    {
        const int j = tid & 15;
        float sn, cs;
        __sincosf(-(float)M_PI / 64.f * (float)j, &sn, &cs);
        for (int s = 0; s < 2; ++s) {
            const int g = tid + (s << 9);
            const int i = ((g & ~15) << 3) | j;
            cplx xx[8], yy[8];
#pragma unroll
            for (int c = 0; c < 8; ++c) xx[c] = buf[i + c * 16];
            r8f(xx, sn, cs, yy);
#pragma unroll
            for (int c = 0; c < 8; ++c) buf[(i + c * 16) ^ (2 * c)] = yy[c];
        }
        __syncthreads();
    }

    // register-local middle: thread owns elements [16*tid, 16*tid+16).
    {
        cplx v[16];
        float4* bb = (float4*)buf;
        const int K = tid & 7;
#pragma unroll
        for (int p = 0; p < 8; ++p) {
            float4 f = bb[8 * tid + (p ^ K)];
            v[2 * p]     = C2(f.x, f.y);
            v[2 * p + 1] = C2(f.z, f.w);
        }
        cplx xe[8], xo[8], E[8], O[8], t[8];
#pragma unroll
        for (int c = 0; c < 8; ++c) { xe[c] = v[2 * c]; xo[c] = v[2 * c + 1]; }
        r8f(xe, 0.f, 1.f, E);
        r8f(xo, -SIN8, COS8, O);
#pragma unroll
        for (int c = 0; c < 8; ++c) t[c] = E[c] + O[c];   // dist-1 + mask fuse
        r8i(t, 0.f, 1.f, xe);
        r8i(t, SIN8, COS8, xo);
#pragma unroll
        for (int p = 0; p < 8; ++p)
            bb[8 * tid + (p ^ K)] = make_float4(xe[p].x, xe[p].y, xo[p].x, xo[p].y);
    }
    __syncthreads();

    // inv LDS pass Q=16: swizzled reads, plain writes
    {
        const int j = tid & 15;
        float sn, cs;
        __sincosf((float)M_PI / 64.f * (float)j, &sn, &cs);
        for (int s = 0; s < 2; ++s) {
            const int g = tid + (s << 9);
            const int i = ((g & ~15) << 3) | j;
            cplx xx[8], yy[8];
#pragma unroll
            for (int c = 0; c < 8; ++c) xx[c] = buf[(i + c * 16) ^ (2 * c)];
            r8i(xx, sn, cs, yy);
#pragma unroll
            for (int c = 0; c < 8; ++c) buf[i + c * 16] = yy[c];
        }
        __syncthreads();
    }

    // inv LDS pass Q=128
    {
        const int j = tid & 127;
        float sn, cs;
        __sincosf((float)M_PI / 512.f * (float)j, &sn, &cs);
        for (int s = 0; s < 2; ++s) {
            const int g = tid + (s << 9);
            const int i = ((g & ~127) << 3) | j;
            cplx xx[8], yy[8];
#pragma unroll
            for (int c = 0; c < 8; ++c) xx[c] = buf[i + c * 128];
            r8i(xx, sn, cs, yy);
#pragma unroll
            for (int c = 0; c < 8; ++c) buf[i + c * 128] = yy[c];
        }
        __syncthreads();
    }

    // final inv pass Q=1024 fused with normalize + K-CHUNKED store
    {
        const size_t base = ((size_t)(row >> 7) * BPLANE) + (size_t)(row & 127) * 64;
        ushort* zcr = zc + base;
        ushort* zsr = zs + base;
        const int tk = tid & 63;
        const int tcb = tid >> 6;
        for (int s = 0; s < 2; ++s) {
            const int g = tid + (s << 9);
            cplx xx[8], yy[8];
#pragma unroll
            for (int c = 0; c < 8; ++c) xx[c] = buf[g + (c << 10)];
            float sn, cs;
            __sincosf((float)M_PI / 4096.f * (float)g, &sn, &cs);
            r8i(xx, sn, cs, yy);
#pragma unroll
            for (int c = 0; c < 8; ++c) {
                cplx vv = yy[c];
                float n2 = vv.x * vv.x + vv.y * vv.y;
                float cc = 1.f, ss = 0.f;
                if (n2 > 0.f) { float inv = rsqrtf(n2); cc = vv.x * inv; ss = vv.y * inv; }
                const int tc = tcb + s * 8 + c * 16;          // t>>6
                zcr[(size_t)tc * TCHUNK + tk] = f2bf(cc);
                zsr[(size_t)tc * TCHUNK + tk] = f2bf(ss);
            }
        }
    }
}

// MFMA Gram partials — R24: diagnostic reverted (single pass); config from
// the session-best 162.4-us run (R10): depth-3 pipeline, 3 x 16 KiB LDS
// (48 KiB -> 2 blocks/CU with VGPR ~110), NKCHUNK=32 (512 blocks),
// KSTAGE=32/NITER=8, counted vmcnt(4)->(2)->(0), column-major swizzle
// (measured-0-conflict bank pattern), contiguous k-chunked reads,
// linear LDS dest + pre-swizzled global src (rule #21). R16 diagnostic:
// gram_single ~30-55 us; both 2-blocks/CU-era totals (162.4, 168.5) beat
// every 1-block/CU-era total (>=172.8).
__global__ __launch_bounds__(512, 4) void gram_kernel(const ushort* __restrict__ zc,
                                                      const ushort* __restrict__ zs,
                                                      __half2* __restrict__ partial) {
    const int b = blockIdx.x, kc = blockIdx.y;
    const int tid = threadIdx.x;
    const int wave = tid >> 6;
    const int lane = tid & 63;
    const int wr = wave & 3, wcol = wave >> 2;
    const int lane31 = tid & 31;
    const int half = (tid >> 5) & 1;

    __shared__ __align__(16) ushort sZ[3 * GBUF];   // 48 KiB

    f32x16 accRe[2], accIm[2];
#pragma unroll
    for (int v = 0; v < 2; ++v)
#pragma unroll
        for (int r = 0; r < 16; ++r) { accRe[v][r] = 0.f; accIm[v][r] = 0.f; }

    // kc covers 4 global t-slabs; stage it covers half-slab (it&1) of slab (it>>1).
    const size_t base = (size_t)b * BPLANE + (size_t)kc * 4 * TCHUNK;

    const ushort* gsrc[2];
    int lbase[2];
#pragma unroll
    for (int q = 0; q < 2; ++q) {
        int L = (q * 8 + wave) * 64 + lane;   // 0..1023
        int plane = L >> 9;
        int P = L & 511;
        int g = P >> 6;
        int s = P & 63;
        int r = g * 16 + (s & 15);
        int c = (s >> 4) ^ (r & 3);
        gsrc[q] = (plane ? zs : zc) + base + (size_t)r * 64 + (size_t)c * 8;
        lbase[q] = (q * 8 + wave) * 512;
    }

#define STAGE(IT, BUF) do {                                                        \
        _Pragma("unroll")                                                          \
        for (int q = 0; q < 2; ++q)                                                \
            __builtin_amdgcn_global_load_lds(                                      \
                (gld_src_t*)(gsrc[q] + (size_t)((IT) >> 1) * TCHUNK                \
                                     + (size_t)((IT) & 1) * 32),                   \
                (gld_dst_t*)&sZ[(BUF) * GBUF + lbase[q]], 16, 0, 0);               \
    } while (0)

    STAGE(0, 0);
    STAGE(1, 1);
    STAGE(2, 2);

#pragma unroll
    for (int it = 0; it < NITER; ++it) {
        if (it <= NITER - 3)      { asm volatile("s_waitcnt vmcnt(4)" ::: "memory"); }
        else if (it == NITER - 2) { asm volatile("s_waitcnt vmcnt(2)" ::: "memory"); }
        else                      { asm volatile("s_waitcnt vmcnt(0)" ::: "memory"); }
        __builtin_amdgcn_sched_barrier(0);
        __builtin_amdgcn_s_barrier();

        const ushort* S = sZ + (it % 3) * GBUF;
#pragma unroll
        for (int kb = 0; kb < KSTAGE; kb += 16) {
            const int cA = (kb >> 3) + half;                   // chunk 0..3
            const int rowA = wr * 32 + lane31;
            const int aoff = ((rowA >> 4) << 9) + ((cA ^ (rowA & 3)) << 7) + ((rowA & 15) << 3);
            bf16x8 aC = *(const bf16x8*)&S[aoff];
            bf16x8 aS = *(const bf16x8*)&S[GSP + aoff];
            bf16x8 aCn;
#pragma unroll
            for (int r = 0; r < 8; ++r) aCn[r] = (short)(aC[r] ^ (short)0x8000);
            bf16x8 bC[2], bS[2];
#pragma unroll
            for (int v = 0; v < 2; ++v) {
                const int rowB = wcol * 64 + v * 32 + lane31;
                const int boff = ((rowB >> 4) << 9) + ((cA ^ (rowB & 3)) << 7) + ((rowB & 15) << 3);
                bC[v] = *(const bf16x8*)&S[boff];
                bS[v] = *(const bf16x8*)&S[GSP + boff];
            }
            accRe[0] = __builtin_amdgcn_mfma_f32_32x32x16_bf16(aC,  bC[0], accRe[0], 0, 0, 0);
            accRe[1] = __builtin_amdgcn_mfma_f32_32x32x16_bf16(aC,  bC[1], accRe[1], 0, 0, 0);
            accIm[0] = __builtin_amdgcn_mfma_f32_32x32x16_bf16(aS,  bC[0], accIm[0], 0, 0, 0);
            accIm[1] = __builtin_amdgcn_mfma_f32_32x32x16_bf16(aS,  bC[1], accIm[1], 0, 0, 0);
            accRe[0] = __builtin_amdgcn_mfma_f32_32x32x16_bf16(aS,  bS[0], accRe[0], 0, 0, 0);
            accRe[1] = __builtin_amdgcn_mfma_f32_32x32x16_bf16(aS,  bS[1], accRe[1], 0, 0, 0);
            accIm[0] = __builtin_amdgcn_mfma_f32_32x32x16_bf16(aCn, bS[0], accIm[0], 0, 0, 0);
            accIm[1] = __builtin_amdgcn_mfma_f32_32x32x16_bf16(aCn, bS[1], accIm[1], 0, 0, 0);
        }

        barrier_lds_only();
        if (it + 3 < NITER) STAGE(it + 3, it % 3);
    }
#undef STAGE

    // C/D layout (verified m74/m101): col=lane&31, row=(reg&3)+8*(reg>>2)+4*(lane>>5)
    __half2* pb = partial + ((size_t)(kc * BATCH + b) << 14);
#pragma unroll
    for (int v = 0; v < 2; ++v)
#pragma unroll
        for (int r = 0; r < 16; ++r) {
            int rrow = (r & 3) + 8 * (r >> 2) + 4 * half;
            int i = wr * 32 + rrow;
            int j = wcol * 64 + v * 32 + lane31;
            pb[i * CHN + j] = __floats2half2_rn(accRe[v][r], accIm[v][r]);
        }
}

// Vectorized reduce — 4 outputs/thread, uint4 loads, float4 store.
__global__ __launch_bounds__(256) void reduce_kernel(const __half2* __restrict__ partial,
                                                     float* __restrict__ out) {
    const size_t n = (size_t)BATCH * CHN * CHN;
    const size_t i4 = ((size_t)blockIdx.x * 256 + threadIdx.x) * 4;
    if (i4 >= n) return;
    float re[4] = {0.f, 0.f, 0.f, 0.f}, im[4] = {0.f, 0.f, 0.f, 0.f};
#pragma unroll
    for (int c = 0; c < NKCHUNK; ++c) {
        uint4 u = *(const uint4*)&partial[(size_t)c * n + i4];
        const __half2* h = (const __half2*)&u;
#pragma unroll
        for (int k = 0; k < 4; ++k) {
            float2 p = __half22float2(h[k]);
            re[k] += p.x;
            im[k] += p.y;
        }
    }
    float4 o;
    o.x = sqrtf(re[0] * re[0] + im[0] * im[0]) * (1.0f / (float)T_LEN);
    o.y = sqrtf(re[1] * re[1] + im[1] * im[1]) * (1.0f / (float)T_LEN);
    o.z = sqrtf(re[2] * re[2] + im[2] * im[2]) * (1.0f / (float)T_LEN);
    o.w = sqrtf(re[3] * re[3] + im[3] * im[3]) * (1.0f / (float)T_LEN);
    *(float4*)&out[i4] = o;
}

extern "C" void kernel_launch(void* const* d_in, const int* in_sizes, int n_in,
                              void* d_out, int out_size, void* d_ws, size_t ws_size,
                              hipStream_t stream) {
    const float* x = (const float*)d_in[0];
    float* out = (float*)d_out;

    const size_t plane_elems = (size_t)BATCH * CHN * T_LEN;                 // 16.8M
    ushort* zc = (ushort*)d_ws;                                             // 33.55 MB
    ushort* zs = zc + plane_elems;                                          // +33.55 MB
    __half2* partial = (__half2*)((char*)d_ws + 2 * plane_elems * sizeof(ushort)); // +33.55 MB (NKCHUNK=32)

    fft_analytic_kernel<<<BATCH * CHN, 512, 0, stream>>>(x, zc, zs);

    dim3 g2(BATCH, NKCHUNK);
    gram_kernel<<<g2, 512, 0, stream>>>(zc, zs, partial);

    const int n_out = BATCH * CHN * CHN;                                    // 262144
    reduce_kernel<<<n_out / (256 * 4), 256, 0, stream>>>(partial, out);
}

// Round 18
// 168.823 us; speedup vs baseline: 1.1484x; 1.0704x over previous
//
#include <hip/hip_runtime.h>
#include <hip/hip_fp16.h>
#include <math.h>

#define T_LEN 8192
#define CHN 128
#define BATCH 16
#define NKCHUNK 32   // k-chunk = 256 -> grid 16x32 = 512 blocks
#define KSTAGE 64    // k elems per LDS buffer (R9 config: depth-2, 64 KiB)
#define NITER (T_LEN / NKCHUNK / KSTAGE)   // = 4 stage iterations per block

typedef short bf16x8 __attribute__((ext_vector_type(8)));
typedef float f32x16 __attribute__((ext_vector_type(16)));

// Native-vector complex type -> packed v_pk_* fp32 codegen (R8: -3 us fft).
typedef float cplx __attribute__((ext_vector_type(2)));
__device__ __forceinline__ cplx C2(float x, float y) { cplx r; r.x = x; r.y = y; return r; }

#define SIN8 0.3826834323650898f
#define COS8 0.9238795325112868f

// zc/zs K-CHUNKED layout [b][t>>6][chan][t&63] (contiguous gram reads).
#define TCHUNK 8192              // ushorts per [tc] slab: 128 chan x 64 k
#define BPLANE (128 * TCHUNK)    // ushorts per batch per plane (= CHN*T_LEN)

// gram LDS geometry (R9/R15-era): UNPADDED 64-ushort rows + XOR row-swizzle.
// Chunk c of row r lives at slot (c ^ (r&7)); staging permutes the per-lane
// GLOBAL source by the same involution (rule #21), LDS dest stays linear.
#define KROW 64                  // ushorts per row
#define SPLANE (128 * KROW)      // 16 KiB per plane
#define BUFSZ (2 * SPLANE)       // 32 KiB per buffer (zc+zs planes)

typedef const __attribute__((address_space(1))) uint gld_src_t;
typedef __attribute__((address_space(3))) uint gld_dst_t;

__device__ __forceinline__ ushort f2bf(float f) {
    unsigned u = __float_as_uint(f);
    unsigned r = (u + 0x7fffu + ((u >> 16) & 1u)) >> 16;
    return (ushort)r;
}

__device__ __forceinline__ void barrier_lds_only() {
    asm volatile("s_waitcnt lgkmcnt(0)" ::: "memory");
    __builtin_amdgcn_s_barrier();
}

__device__ __forceinline__ cplx cmul(cplx a, cplx b) {
    cplx t = a.yy * b.yx;            // {ay*by, ay*bx}  (pk_mul)
    cplx r = a.xx * b;               // {ax*bx, ax*by}  (pk_mul)
    return C2(r.x - t.x, r.y + t.y);
}

__device__ __forceinline__ void r4f(cplx x0, cplx x1, cplx x2, cplx x3,
                                    cplx wa, cplx wb, cplx wc,
                                    cplx& y0, cplx& y1, cplx& y2, cplx& y3) {
    cplx t0 = x0 + x2, t1 = x0 - x2;
    cplx t2 = x1 + x3, t3 = x1 - x3;
    y0 = t0 + t2;
    y1 = cmul(t0 - t2, wb);
    y2 = cmul(C2(t1.x + t3.y, t1.y - t3.x), wa);
    y3 = cmul(C2(t1.x - t3.y, t1.y + t3.x), wc);
}

__device__ __forceinline__ void r4i(cplx x0, cplx x1, cplx x2, cplx x3,
                                    cplx wa, cplx wb, cplx wc,
                                    cplx& y0, cplx& y1, cplx& y2, cplx& y3) {
    cplx a1 = cmul(x1, wb);
    cplx a2 = cmul(x2, wa);
    cplx a3 = cmul(x3, wc);
    cplx u0 = x0 + a1, u1 = x0 - a1;
    cplx p = a2 + a3;
    cplx m = C2(-(a2.y - a3.y), a2.x - a3.x);
    y0 = u0 + p; y2 = u0 - p;
    y1 = u1 + m; y3 = u1 - m;
}

__device__ __forceinline__ void r8f(const cplx* x, float sn, float cs, cplx* y) {
    const float r22 = 0.70710678118654752f;
    cplx w1 = C2(cs, sn);
    cplx w2 = C2(cs * cs - sn * sn, 2.f * cs * sn);
    cplx w4 = cmul(w2, w2);
    cplx w6 = cmul(w4, w2);
    cplx u0 = x[0] + x[4], u1 = x[1] + x[5], u2 = x[2] + x[6], u3 = x[3] + x[7];
    cplx e0 = cmul(x[0] - x[4], w1);
    cplx e1 = cmul(x[1] - x[5], w1);
    cplx e2 = cmul(x[2] - x[6], w1);
    cplx e3 = cmul(x[3] - x[7], w1);
    cplx v0 = e0;
    cplx v1 = C2(r22 * (e1.x + e1.y), r22 * (e1.y - e1.x));
    cplx v2 = C2(e2.y, -e2.x);
    cplx v3 = C2(r22 * (e3.y - e3.x), -r22 * (e3.x + e3.y));
    r4f(u0, u1, u2, u3, w2, w4, w6, y[0], y[1], y[2], y[3]);
    r4f(v0, v1, v2, v3, w2, w4, w6, y[4], y[5], y[6], y[7]);
}

// Pass-A specialization: inputs pure real (imag = 0).
__device__ __forceinline__ void r8f_real(const float* x, float sn, float cs, cplx* y) {
    const float r22 = 0.70710678118654752f;
    cplx w2 = C2(cs * cs - sn * sn, 2.f * cs * sn);
    cplx w4 = cmul(w2, w2);
    cplx w6 = cmul(w4, w2);
    float u0 = x[0] + x[4], u1 = x[1] + x[5], u2 = x[2] + x[6], u3 = x[3] + x[7];
    float d0 = x[0] - x[4], d1 = x[1] - x[5], d2 = x[2] - x[6], d3 = x[3] - x[7];
    cplx e1 = C2(d1 * cs, d1 * sn);
    cplx e2 = C2(d2 * cs, d2 * sn);
    cplx e3 = C2(d3 * cs, d3 * sn);
    cplx v0 = C2(d0 * cs, d0 * sn);
    cplx v1 = C2(r22 * (e1.x + e1.y), r22 * (e1.y - e1.x));
    cplx v2 = C2(e2.y, -e2.x);
    cplx v3 = C2(r22 * (e3.y - e3.x), -r22 * (e3.x + e3.y));
    float t0 = u0 + u2, t1 = u0 - u2, t2 = u1 + u3, t3 = u1 - u3;
    y[0] = C2(t0 + t2, 0.f);
    float s1 = t0 - t2;
    y[1] = C2(s1 * w4.x, s1 * w4.y);
    y[2] = cmul(C2(t1, -t3), w2);
    y[3] = cmul(C2(t1, t3), w6);
    r4f(v0, v1, v2, v3, w2, w4, w6, y[4], y[5], y[6], y[7]);
}

__device__ __forceinline__ void r8i(const cplx* x, float sn, float cs, cplx* y) {
    const float r22 = 0.70710678118654752f;
    cplx w1 = C2(cs, sn);
    cplx w2 = C2(cs * cs - sn * sn, 2.f * cs * sn);
    cplx w4 = cmul(w2, w2);
    cplx w6 = cmul(w4, w2);
    cplx g0, g1, g2, g3, g4, g5, g6, g7;
    r4i(x[0], x[1], x[2], x[3], w2, w4, w6, g0, g1, g2, g3);
    r4i(x[4], x[5], x[6], x[7], w2, w4, w6, g4, g5, g6, g7);
    cplx t0 = cmul(g4, w1);
    cplx e1 = cmul(g5, w1);
    cplx e2 = cmul(g6, w1);
    cplx e3 = cmul(g7, w1);
    cplx t1 = C2(r22 * (e1.x - e1.y), r22 * (e1.x + e1.y));
    cplx t2 = C2(-e2.y, e2.x);
    cplx t3 = C2(-r22 * (e3.x + e3.y), r22 * (e3.x - e3.y));
    y[0] = g0 + t0; y[4] = g0 - t0;
    y[1] = g1 + t1; y[5] = g1 - t1;
    y[2] = g2 + t2; y[6] = g2 - t2;
    y[3] = g3 + t3; y[7] = g3 - t3;
}

// fft: proven R13/R15 structure (74-77 us across 6 sessions). Structural
// floor: VALU-issue ~51 us + stalls at 2 blocks/CU (64 KiB LDS cap).
// Attacked 5x: 1024-thr (spills), twiddle-chain hoist (-25% regression,
// cross-barrier liveness), fused s-halves (-28%, allocator serialized),
// pass-local sincos hoist (null). Do not touch without per-kernel counters.
__global__ __launch_bounds__(512, 4) void fft_analytic_kernel(const float* __restrict__ x,
                                                              ushort* __restrict__ zc,
                                                              ushort* __restrict__ zs) {
    __shared__ __align__(16) cplx buf[T_LEN];   // 64 KiB
    const int tid = threadIdx.x;
    const int row = blockIdx.x;
    const float* xr = x + ((size_t)row << 13);

    // fwd pass Q=1024 fused with global load (x real; imag folds away)
    for (int s = 0; s < 2; ++s) {
        const int g = tid + (s << 9);
        float X[8];
        cplx Y[8];
#pragma unroll
        for (int c = 0; c < 8; ++c) X[c] = xr[g + (c << 10)];
        float sn, cs;
        __sincosf(-(float)M_PI / 4096.f * (float)g, &sn, &cs);
        r8f_real(X, sn, cs, Y);
#pragma unroll
        for (int c = 0; c < 8; ++c) buf[g + (c << 10)] = Y[c];
    }
    __syncthreads();

    // fwd LDS pass Q=128 (sincos hoisted; j s-invariant)
    {
        const int j = tid & 127;
        float sn, cs;
        __sincosf(-(float)M_PI / 512.f * (float)j, &sn, &cs);
        for (int s = 0; s < 2; ++s) {
            const int g = tid + (s << 9);
            const int i = ((g & ~127) << 3) | j;
            cplx xx[8], yy[8];
#pragma unroll
            for (int c = 0; c < 8; ++c) xx[c] = buf[i + c * 128];
            r8f(xx, sn, cs, yy);
#pragma unroll
            for (int c = 0; c < 8; ++c) buf[i + c * 128] = yy[c];
        }
        __syncthreads();
    }

    // fwd LDS pass Q=16: plain reads, swizzled writes (slot = idx ^ 2c)
    {
        const int j = tid & 15;
        float sn, cs;
        __sincosf(-(float)M_PI / 64.f * (float)j, &sn, &cs);
        for (int s = 0; s < 2; ++s) {
            const int g = tid + (s << 9);
            const int i = ((g & ~15) << 3) | j;
            cplx xx[8], yy[8];
#pragma unroll
            for (int c = 0; c < 8; ++c) xx[c] = buf[i + c * 16];
            r8f(xx, sn, cs, yy);
#pragma unroll
            for (int c = 0; c < 8; ++c) buf[(i + c * 16) ^ (2 * c)] = yy[c];
        }
        __syncthreads();
    }

    // register-local middle: thread owns elements [16*tid, 16*tid+16).
    {
        cplx v[16];
        float4* bb = (float4*)buf;
        const int K = tid & 7;
#pragma unroll
        for (int p = 0; p < 8; ++p) {
            float4 f = bb[8 * tid + (p ^ K)];
            v[2 * p]     = C2(f.x, f.y);
            v[2 * p + 1] = C2(f.z, f.w);
        }
        cplx xe[8], xo[8], E[8], O[8], t[8];
#pragma unroll
        for (int c = 0; c < 8; ++c) { xe[c] = v[2 * c]; xo[c] = v[2 * c + 1]; }
        r8f(xe, 0.f, 1.f, E);
        r8f(xo, -SIN8, COS8, O);
#pragma unroll
        for (int c = 0; c < 8; ++c) t[c] = E[c] + O[c];   // dist-1 + mask fuse
        r8i(t, 0.f, 1.f, xe);
        r8i(t, SIN8, COS8, xo);
#pragma unroll
        for (int p = 0; p < 8; ++p)
            bb[8 * tid + (p ^ K)] = make_float4(xe[p].x, xe[p].y, xo[p].x, xo[p].y);
    }
    __syncthreads();

    // inv LDS pass Q=16: swizzled reads, plain writes
    {
        const int j = tid & 15;
        float sn, cs;
        __sincosf((float)M_PI / 64.f * (float)j, &sn, &cs);
        for (int s = 0; s < 2; ++s) {
            const int g = tid + (s << 9);
            const int i = ((g & ~15) << 3) | j;
            cplx xx[8], yy[8];
#pragma unroll
            for (int c = 0; c < 8; ++c) xx[c] = buf[(i + c * 16) ^ (2 * c)];
            r8i(xx, sn, cs, yy);
#pragma unroll
            for (int c = 0; c < 8; ++c) buf[i + c * 16] = yy[c];
        }
        __syncthreads();
    }

    // inv LDS pass Q=128
    {
        const int j = tid & 127;
        float sn, cs;
        __sincosf((float)M_PI / 512.f * (float)j, &sn, &cs);
        for (int s = 0; s < 2; ++s) {
            const int g = tid + (s << 9);
            const int i = ((g & ~127) << 3) | j;
            cplx xx[8], yy[8];
#pragma unroll
            for (int c = 0; c < 8; ++c) xx[c] = buf[i + c * 128];
            r8i(xx, sn, cs, yy);
#pragma unroll
            for (int c = 0; c < 8; ++c) buf[i + c * 128] = yy[c];
        }
        __syncthreads();
    }

    // final inv pass Q=1024 fused with normalize + K-CHUNKED store
    {
        const size_t base = ((size_t)(row >> 7) * BPLANE) + (size_t)(row & 127) * 64;
        ushort* zcr = zc + base;
        ushort* zsr = zs + base;
        const int tk = tid & 63;
        const int tcb = tid >> 6;
        for (int s = 0; s < 2; ++s) {
            const int g = tid + (s << 9);
            cplx xx[8], yy[8];
#pragma unroll
            for (int c = 0; c < 8; ++c) xx[c] = buf[g + (c << 10)];
            float sn, cs;
            __sincosf((float)M_PI / 4096.f * (float)g, &sn, &cs);
            r8i(xx, sn, cs, yy);
#pragma unroll
            for (int c = 0; c < 8; ++c) {
                cplx vv = yy[c];
                float n2 = vv.x * vv.x + vv.y * vv.y;
                float cc = 1.f, ss = 0.f;
                if (n2 > 0.f) { float inv = rsqrtf(n2); cc = vv.x * inv; ss = vv.y * inv; }
                const int tc = tcb + s * 8 + c * 16;          // t>>6
                zcr[(size_t)tc * TCHUNK + tk] = f2bf(cc);
                zsr[(size_t)tc * TCHUNK + tk] = f2bf(ss);
            }
        }
    }
}

// MFMA Gram partials — R25 lock-in: the R9 config exactly (the best
// verified total with proven fft: 168.5; sibling R8: 172.2). Depth-2 DMA
// pipeline, KSTAGE=64, 2 x 32 KiB buffers (64 KiB LDS), NKCHUNK=32
// (512 blocks, 2/CU), counted vmcnt(4) steady / (0) tail, XOR row-swizzle
// with pre-swizzled contiguous global source (rule #21). Session evidence:
// all gram variants (depth 2/3/4/8, 256/512 blocks) within cross-session
// noise; gram_single ~30-55 us (R16 x2-diagnostic bound).
__global__ __launch_bounds__(512, 4) void gram_kernel(const ushort* __restrict__ zc,
                                                      const ushort* __restrict__ zs,
                                                      __half2* __restrict__ partial) {
    const int b = blockIdx.x, kc = blockIdx.y;
    const int tid = threadIdx.x;
    const int wave = tid >> 6;
    const int lane = tid & 63;
    const int wr = wave & 3, wcol = wave >> 2;
    const int lane31 = tid & 31;
    const int half = (tid >> 5) & 1;

    __shared__ __align__(16) ushort sZ[2 * BUFSZ];   // 64 KiB

    f32x16 accRe[2], accIm[2];
#pragma unroll
    for (int v = 0; v < 2; ++v)
#pragma unroll
        for (int r = 0; r < 16; ++r) { accRe[v][r] = 0.f; accIm[v][r] = 0.f; }

    // kc covers 4 global t-slabs (KSTAGE=64 = one full slab per stage).
    const size_t base = (size_t)b * BPLANE + (size_t)(kc * NITER) * TCHUNK;

    const ushort* gsrc[4];
    int lbase[4];
#pragma unroll
    for (int q = 0; q < 4; ++q) {
        int L = (q * 8 + wave) * 64 + lane;   // linear 16B-chunk id in buffer
        int plane = L >> 10;
        int r = (L >> 3) & 127;
        int slot = L & 7;
        int c = slot ^ (r & 7);
        gsrc[q] = (plane ? zs : zc) + base + (size_t)r * 64 + (size_t)c * 8;
        lbase[q] = (q * 8 + wave) * 512;
    }

#define STAGE(IT, BUF) do {                                                        \
        _Pragma("unroll")                                                          \
        for (int q = 0; q < 4; ++q)                                                \
            __builtin_amdgcn_global_load_lds(                                      \
                (gld_src_t*)(gsrc[q] + (size_t)(IT) * TCHUNK),                     \
                (gld_dst_t*)&sZ[(BUF) * BUFSZ + lbase[q]], 16, 0, 0);              \
    } while (0)

    STAGE(0, 0);
    STAGE(1, 1);

#pragma unroll
    for (int it = 0; it < NITER; ++it) {
        if (it < NITER - 1) { asm volatile("s_waitcnt vmcnt(4)" ::: "memory"); }
        else                { asm volatile("s_waitcnt vmcnt(0)" ::: "memory"); }
        __builtin_amdgcn_sched_barrier(0);
        __builtin_amdgcn_s_barrier();

        const ushort* S = sZ + (it & 1) * BUFSZ;
#pragma unroll
        for (int kb = 0; kb < KSTAGE; kb += 16) {
            const int cA = (kb >> 3) + half;
            const int rowA = wr * 32 + lane31;
            const int aoff = rowA * KROW + ((cA ^ (rowA & 7)) << 3);
            bf16x8 aC = *(const bf16x8*)&S[aoff];
            bf16x8 aS = *(const bf16x8*)&S[SPLANE + aoff];
            bf16x8 aCn;
#pragma unroll
            for (int r = 0; r < 8; ++r) aCn[r] = (short)(aC[r] ^ (short)0x8000);
            bf16x8 bC[2], bS[2];
#pragma unroll
            for (int v = 0; v < 2; ++v) {
                const int rowB = wcol * 64 + v * 32 + lane31;
                const int boff = rowB * KROW + ((cA ^ (rowB & 7)) << 3);
                bC[v] = *(const bf16x8*)&S[boff];
                bS[v] = *(const bf16x8*)&S[SPLANE + boff];
            }
            accRe[0] = __builtin_amdgcn_mfma_f32_32x32x16_bf16(aC,  bC[0], accRe[0], 0, 0, 0);
            accRe[1] = __builtin_amdgcn_mfma_f32_32x32x16_bf16(aC,  bC[1], accRe[1], 0, 0, 0);
            accIm[0] = __builtin_amdgcn_mfma_f32_32x32x16_bf16(aS,  bC[0], accIm[0], 0, 0, 0);
            accIm[1] = __builtin_amdgcn_mfma_f32_32x32x16_bf16(aS,  bC[1], accIm[1], 0, 0, 0);
            accRe[0] = __builtin_amdgcn_mfma_f32_32x32x16_bf16(aS,  bS[0], accRe[0], 0, 0, 0);
            accRe[1] = __builtin_amdgcn_mfma_f32_32x32x16_bf16(aS,  bS[1], accRe[1], 0, 0, 0);
            accIm[0] = __builtin_amdgcn_mfma_f32_32x32x16_bf16(aCn, bS[0], accIm[0], 0, 0, 0);
            accIm[1] = __builtin_amdgcn_mfma_f32_32x32x16_bf16(aCn, bS[1], accIm[1], 0, 0, 0);
        }

        barrier_lds_only();
        if (it + 2 < NITER) STAGE(it + 2, it & 1);
    }
#undef STAGE

    // C/D layout (verified m74/m101): col=lane&31, row=(reg&3)+8*(reg>>2)+4*(lane>>5)
    __half2* pb = partial + ((size_t)(kc * BATCH + b) << 14);
#pragma unroll
    for (int v = 0; v < 2; ++v)
#pragma unroll
        for (int r = 0; r < 16; ++r) {
            int rrow = (r & 3) + 8 * (r >> 2) + 4 * half;
            int i = wr * 32 + rrow;
            int j = wcol * 64 + v * 32 + lane31;
            pb[i * CHN + j] = __floats2half2_rn(accRe[v][r], accIm[v][r]);
        }
}

// Vectorized reduce — 4 outputs/thread, uint4 loads, float4 store.
__global__ __launch_bounds__(256) void reduce_kernel(const __half2* __restrict__ partial,
                                                     float* __restrict__ out) {
    const size_t n = (size_t)BATCH * CHN * CHN;
    const size_t i4 = ((size_t)blockIdx.x * 256 + threadIdx.x) * 4;
    if (i4 >= n) return;
    float re[4] = {0.f, 0.f, 0.f, 0.f}, im[4] = {0.f, 0.f, 0.f, 0.f};
#pragma unroll
    for (int c = 0; c < NKCHUNK; ++c) {
        uint4 u = *(const uint4*)&partial[(size_t)c * n + i4];
        const __half2* h = (const __half2*)&u;
#pragma unroll
        for (int k = 0; k < 4; ++k) {
            float2 p = __half22float2(h[k]);
            re[k] += p.x;
            im[k] += p.y;
        }
    }
    float4 o;
    o.x = sqrtf(re[0] * re[0] + im[0] * im[0]) * (1.0f / (float)T_LEN);
    o.y = sqrtf(re[1] * re[1] + im[1] * im[1]) * (1.0f / (float)T_LEN);
    o.z = sqrtf(re[2] * re[2] + im[2] * im[2]) * (1.0f / (float)T_LEN);
    o.w = sqrtf(re[3] * re[3] + im[3] * im[3]) * (1.0f / (float)T_LEN);
    *(float4*)&out[i4] = o;
}

extern "C" void kernel_launch(void* const* d_in, const int* in_sizes, int n_in,
                              void* d_out, int out_size, void* d_ws, size_t ws_size,
                              hipStream_t stream) {
    const float* x = (const float*)d_in[0];
    float* out = (float*)d_out;

    const size_t plane_elems = (size_t)BATCH * CHN * T_LEN;                 // 16.8M
    ushort* zc = (ushort*)d_ws;                                             // 33.55 MB
    ushort* zs = zc + plane_elems;                                          // +33.55 MB
    __half2* partial = (__half2*)((char*)d_ws + 2 * plane_elems * sizeof(ushort)); // +33.55 MB (NKCHUNK=32)

    fft_analytic_kernel<<<BATCH * CHN, 512, 0, stream>>>(x, zc, zs);

    dim3 g2(BATCH, NKCHUNK);
    gram_kernel<<<g2, 512, 0, stream>>>(zc, zs, partial);

    const int n_out = BATCH * CHN * CHN;                                    // 262144
    reduce_kernel<<<n_out / (256 * 4), 256, 0, stream>>>(partial, out);
}